// Round 3
// baseline (414.535 us; speedup 1.0000x reference)
//
#include <hip/hip_runtime.h>
#include <hip/hip_bf16.h>

// Problem constants
#define BQ 8
#define NATOM 512
#define NFEAT 42
#define NNEIGH 100
#define H1 64
#define H2 32

// ws layout (floats):
//   [0, 172368)            padded dE, shape (B, NATOM+1, NFEAT), row 0 per image zeroed
//   [172368, 172368+4096)  Ei in f32 (for Etot reduction)
#define WS_DE 0
#define WS_EI (BQ * (NATOM + 1) * NFEAT)

// ---------------------------------------------------------------- kernel 1
// thread = atom. 64 blocks x 64 threads; type is block-uniform (atoms 0-255 -> t=0).
__global__ __launch_bounds__(64) void k_ei(
    const float* __restrict__ image,
    const float* __restrict__ W0, const float* __restrict__ b0,
    const float* __restrict__ W1, const float* __restrict__ b1,
    const float* __restrict__ W2, const float* __restrict__ b2,
    float* __restrict__ dE,          // padded (B, 513, 42) f32
    float* __restrict__ eiF,         // (B*512) f32
    float* __restrict__ outEi)       // f32 output, (B*512)
{
    const int ga = blockIdx.x * 64 + threadIdx.x;   // 0..4095
    const int b  = ga >> 9;
    const int a  = ga & 511;
    const int t  = a >> 8;                           // block-uniform

    const float* __restrict__ W0r = W0 + t * (H1 * NFEAT);
    const float* __restrict__ b0r = b0 + t * H1;
    const float* __restrict__ W1r = W1 + t * (H2 * H1);
    const float* __restrict__ b1r = b1 + t * H2;
    const float* __restrict__ W2r = W2 + t * H2;
    const float  b2v               = b2[t];

    // load x row (42 f32)
    float x[NFEAT];
    const float* __restrict__ xr = image + (size_t)ga * NFEAT;
    #pragma unroll
    for (int i = 0; i < NFEAT; ++i) x[i] = xr[i];

    // layer 1
    float h0[H1];
    #pragma unroll
    for (int j = 0; j < H1; ++j) {
        float s = b0r[j];
        #pragma unroll
        for (int f = 0; f < NFEAT; ++f) s = fmaf(W0r[j * NFEAT + f], x[f], s);
        h0[j] = tanhf(s);
    }
    // layer 2
    float h1[H2];
    #pragma unroll
    for (int k = 0; k < H2; ++k) {
        float s = b1r[k];
        #pragma unroll
        for (int j = 0; j < H1; ++j) s = fmaf(W1r[k * H1 + j], h0[j], s);
        h1[k] = tanhf(s);
    }
    // output
    float y = b2v;
    #pragma unroll
    for (int k = 0; k < H2; ++k) y = fmaf(W2r[k], h1[k], y);

    eiF[ga]   = y;
    outEi[ga] = y;

    // backward: dE/dx
    float g1[H2];
    #pragma unroll
    for (int k = 0; k < H2; ++k) g1[k] = W2r[k] * (1.0f - h1[k] * h1[k]);

    float g0[H1];
    #pragma unroll
    for (int j = 0; j < H1; ++j) {
        float s = 0.0f;
        #pragma unroll
        for (int k = 0; k < H2; ++k) s = fmaf(g1[k], W1r[k * H1 + j], s);
        g0[j] = s * (1.0f - h0[j] * h0[j]);
    }

    float* __restrict__ dErow = dE + ((size_t)b * (NATOM + 1) + (a + 1)) * NFEAT;
    #pragma unroll
    for (int f = 0; f < NFEAT; ++f) {
        float s = 0.0f;
        #pragma unroll
        for (int j = 0; j < H1; ++j) s = fmaf(g0[j], W0r[j * NFEAT + f], s);
        dErow[f] = s;
    }

    // zero the pad row (neighbor index 0) — first block of each image does it
    if ((blockIdx.x & 7) == 0 && threadIdx.x < NFEAT)
        dE[(size_t)b * (NATOM + 1) * NFEAT + threadIdx.x] = 0.0f;
}

// ---------------------------------------------------------------- kernel 2
// one block per (b, atom). Streams the 50400-byte f32 dfeat slice (HBM-bound).
__global__ __launch_bounds__(256) void k_force(
    const float* __restrict__ dfeat,
    const int* __restrict__ neighbor,
    const float* __restrict__ dE,
    const float* __restrict__ eiF,
    float* __restrict__ out)         // f32 output buffer, 16392 elems
{
    __shared__ __align__(16) float g[NNEIGH * NFEAT];   // 4200 f32 = 16.8 KB
    __shared__ int nb[NNEIGH];
    __shared__ float red[12];

    const int ba  = blockIdx.x;          // 0..4095
    const int b   = ba >> 9;
    const int tid = threadIdx.x;

    if (tid < NNEIGH) nb[tid] = neighbor[(size_t)ba * NNEIGH + tid];
    __syncthreads();

    // gather dE rows of the 100 neighbors into LDS (flat [n*42+f])
    const float* __restrict__ dEb = dE + (size_t)b * (NATOM + 1) * NFEAT;
    for (int e = tid; e < NNEIGH * NFEAT; e += 256) {
        int n = e / NFEAT;
        int f = e - n * NFEAT;
        g[e] = dEb[(size_t)nb[n] * NFEAT + f];
    }
    __syncthreads();

    // stream dfeat: 12600 f32 per (b,a); 12 floats (48B = 3 x float4) per chunk.
    // 12 elems = 4 (n,f)-pairs x 3 force comps -> fixed k pattern; gi*12 % 4 == 0
    // so the 4 g values are one aligned float4.
    const float* __restrict__ df = dfeat + (size_t)ba * (NNEIGH * NFEAT * 3);
    const float4* __restrict__ g4 = (const float4*)g;

    float a0 = 0.f, a1 = 0.f, a2 = 0.f;
    for (int gi = tid; gi < 1050; gi += 256) {
        const float4* p = (const float4*)(df + gi * 12);
        float4 v0 = p[0], v1 = p[1], v2 = p[2];
        float4 gv = g4[gi];

        // pair j uses g value gv[j] and dfeat elements 3j..3j+2 within the chunk
        a0 = fmaf(gv.x, v0.x, a0); a1 = fmaf(gv.x, v0.y, a1); a2 = fmaf(gv.x, v0.z, a2);
        a0 = fmaf(gv.y, v0.w, a0); a1 = fmaf(gv.y, v1.x, a1); a2 = fmaf(gv.y, v1.y, a2);
        a0 = fmaf(gv.z, v1.z, a0); a1 = fmaf(gv.z, v1.w, a1); a2 = fmaf(gv.z, v2.x, a2);
        a0 = fmaf(gv.w, v2.y, a0); a1 = fmaf(gv.w, v2.z, a1); a2 = fmaf(gv.w, v2.w, a2);
    }

    // wave shuffle reduce (width 64), then cross-wave via LDS
    #pragma unroll
    for (int off = 32; off > 0; off >>= 1) {
        a0 += __shfl_down(a0, off, 64);
        a1 += __shfl_down(a1, off, 64);
        a2 += __shfl_down(a2, off, 64);
    }
    const int wave = tid >> 6, lane = tid & 63;
    if (lane == 0) { red[wave * 3] = a0; red[wave * 3 + 1] = a1; red[wave * 3 + 2] = a2; }
    __syncthreads();
    if (tid < 3) {
        float s = red[tid] + red[3 + tid] + red[6 + tid] + red[9 + tid];
        out[8 + BQ * NATOM + (size_t)ba * 3 + tid] = s;
    }

    // block 0 additionally reduces Etot (8 values) from f32 Ei in ws
    if (blockIdx.x == 0) {
        for (int bb = wave * 2; bb < wave * 2 + 2; ++bb) {
            float s = 0.f;
            for (int i = lane; i < NATOM; i += 64) s += eiF[bb * NATOM + i];
            #pragma unroll
            for (int off = 32; off > 0; off >>= 1) s += __shfl_down(s, off, 64);
            if (lane == 0) out[bb] = s;
        }
    }
}

// ---------------------------------------------------------------- launcher
extern "C" void kernel_launch(void* const* d_in, const int* in_sizes, int n_in,
                              void* d_out, int out_size, void* d_ws, size_t ws_size,
                              hipStream_t stream)
{
    const float* image    = (const float*)d_in[0];
    const float* dfeat    = (const float*)d_in[1];
    const int*   neighbor = (const int*)d_in[2];
    // d_in[3] natoms_img unused
    const float* W0 = (const float*)d_in[4];
    const float* b0 = (const float*)d_in[5];
    const float* W1 = (const float*)d_in[6];
    const float* b1 = (const float*)d_in[7];
    const float* W2 = (const float*)d_in[8];
    const float* b2 = (const float*)d_in[9];

    float* wsf  = (float*)d_ws;
    float* dE   = wsf + WS_DE;
    float* eiF  = wsf + WS_EI;
    float* out  = (float*)d_out;

    hipLaunchKernelGGL(k_ei, dim3(64), dim3(64), 0, stream,
                       image, W0, b0, W1, b1, W2, b2, dE, eiF, out + 8);
    hipLaunchKernelGGL(k_force, dim3(4096), dim3(256), 0, stream,
                       dfeat, neighbor, dE, eiF, out);
}

// Round 4
// 311.887 us; speedup vs baseline: 1.3291x; 1.3291x over previous
//
#include <hip/hip_runtime.h>
#include <hip/hip_bf16.h>

// Problem constants
#define BQ 8
#define NATOM 512
#define NFEAT 42
#define NNEIGH 100
#define H1 64
#define H2 32

// ws layout (floats):
//   [0, 172368)            padded dE, shape (B, NATOM+1, NFEAT), row 0 per image zeroed
//   [172368, 172368+4096)  Ei in f32 (for Etot reduction)
#define WS_DE 0
#define WS_EI (BQ * (NATOM + 1) * NFEAT)

// ---------------------------------------------------------------- kernel 1
// one WAVE per atom; 4 atoms per 256-thread block; 1024 blocks.
// Weights LDS-staged once per block (type is block-uniform: 4 | 256).
// W0 rows padded 42->43 (43%32=11, odd -> conflict-free), W1 rows 64->65.
__global__ __launch_bounds__(256) void k_ei(
    const float* __restrict__ image,
    const float* __restrict__ W0, const float* __restrict__ b0,
    const float* __restrict__ W1, const float* __restrict__ b1,
    const float* __restrict__ W2, const float* __restrict__ b2,
    float* __restrict__ dE,          // padded (B, 513, 42) f32
    float* __restrict__ eiF,         // (B*512) f32
    float* __restrict__ outEi)       // f32 output Ei (B*512)
{
    __shared__ float W0s[H1 * 43];       // 2752 f32
    __shared__ float W1s[H2 * 65];       // 2080 f32
    __shared__ float W2s[H2];
    __shared__ float b0s[H1];
    __shared__ float b1s[H2];
    __shared__ float xs[4][44];
    __shared__ float h0s[4][H1];
    __shared__ float g1s[4][H2];
    __shared__ float g0s[4][H1];

    const int tid  = threadIdx.x;
    const int w    = tid >> 6;            // wave id 0..3
    const int lane = tid & 63;
    const int ga   = blockIdx.x * 4 + w;  // global atom 0..4095
    const int b    = ga >> 9;
    const int t    = (blockIdx.x >> 6) & 1;   // type, block-uniform

    // ---- stage weights (coalesced global -> padded LDS)
    for (int e = tid; e < H1 * NFEAT; e += 256) {
        int r = e / NFEAT, c = e - r * NFEAT;
        W0s[r * 43 + c] = W0[t * (H1 * NFEAT) + e];
    }
    for (int e = tid; e < H2 * H1; e += 256) {
        int r = e >> 6, c = e & 63;
        W1s[r * 65 + c] = W1[t * (H2 * H1) + e];
    }
    if (tid < H2) { W2s[tid] = W2[t * H2 + tid]; b1s[tid] = b1[t * H2 + tid]; }
    if (tid >= 64 && tid < 128) b0s[tid - 64] = b0[t * H1 + (tid - 64)];
    // ---- stage x rows (42 f32 per atom)
    if (lane < NFEAT) xs[w][lane] = image[(size_t)ga * NFEAT + lane];
    __syncthreads();

    // ---- layer 1: lane j computes h0[j]
    float s = b0s[lane];
    #pragma unroll
    for (int f = 0; f < NFEAT; ++f) s = fmaf(W0s[lane * 43 + f], xs[w][f], s);
    const float h0 = tanhf(s);
    h0s[w][lane] = h0;
    __syncthreads();

    // ---- layer 2: lane k (both half-waves compute k = lane&31 redundantly)
    const int k = lane & 31;
    s = b1s[k];
    #pragma unroll
    for (int j = 0; j < H1; ++j) s = fmaf(W1s[k * 65 + j], h0s[w][j], s);
    const float h1 = tanhf(s);

    // ---- output y = sum_k W2[k]*h1[k]  (reduce over lower 32 lanes)
    float p = W2s[k] * h1;
    p += __shfl_down(p, 16, 64);
    p += __shfl_down(p, 8, 64);
    p += __shfl_down(p, 4, 64);
    p += __shfl_down(p, 2, 64);
    p += __shfl_down(p, 1, 64);
    if (lane == 0) {
        float y = p + b2[t];
        eiF[ga]   = y;
        outEi[ga] = y;
    }

    // ---- backward
    const float g1 = W2s[k] * (1.0f - h1 * h1);
    if (lane < H2) g1s[w][lane] = g1;
    __syncthreads();

    // g0[j]: lane j
    s = 0.0f;
    #pragma unroll
    for (int kk = 0; kk < H2; ++kk) s = fmaf(g1s[w][kk], W1s[kk * 65 + lane], s);
    const float g0 = s * (1.0f - h0 * h0);
    g0s[w][lane] = g0;
    __syncthreads();

    // dE row: lane f
    if (lane < NFEAT) {
        s = 0.0f;
        #pragma unroll
        for (int j = 0; j < H1; ++j) s = fmaf(g0s[w][j], W0s[j * 43 + lane], s);
        dE[((size_t)b * (NATOM + 1) + (ga & 511) + 1) * NFEAT + lane] = s;
    }

    // zero the pad row (neighbor index 0) — first block of each image
    if ((blockIdx.x & 127) == 0 && tid < NFEAT)
        dE[(size_t)(blockIdx.x >> 7) * (NATOM + 1) * NFEAT + tid] = 0.0f;
}

// ---------------------------------------------------------------- kernel 2
// one block per (b, atom). Streams the 50400-byte f32 dfeat slice (HBM-bound).
__global__ __launch_bounds__(256) void k_force(
    const float* __restrict__ dfeat,
    const int* __restrict__ neighbor,
    const float* __restrict__ dE,
    const float* __restrict__ eiF,
    float* __restrict__ out)         // f32 output buffer, 16392 elems
{
    __shared__ __align__(16) float g[NNEIGH * NFEAT];   // 4200 f32 = 16.8 KB
    __shared__ int nb[NNEIGH];
    __shared__ float red[12];

    const int ba  = blockIdx.x;          // 0..4095
    const int b   = ba >> 9;
    const int tid = threadIdx.x;

    if (tid < NNEIGH) nb[tid] = neighbor[(size_t)ba * NNEIGH + tid];
    __syncthreads();

    // gather dE rows of the 100 neighbors into LDS (flat [n*42+f])
    const float* __restrict__ dEb = dE + (size_t)b * (NATOM + 1) * NFEAT;
    for (int e = tid; e < NNEIGH * NFEAT; e += 256) {
        int n = e / NFEAT;
        int f = e - n * NFEAT;
        g[e] = dEb[(size_t)nb[n] * NFEAT + f];
    }
    __syncthreads();

    // stream dfeat: 12600 f32 per (b,a); 12 floats (48B = 3 x float4) per chunk.
    // 12 elems = 4 (n,f)-pairs x 3 force comps -> fixed k pattern; gi*12 % 4 == 0
    // so the 4 g values are one aligned float4.
    const float* __restrict__ df = dfeat + (size_t)ba * (NNEIGH * NFEAT * 3);
    const float4* __restrict__ g4 = (const float4*)g;

    float a0 = 0.f, a1 = 0.f, a2 = 0.f;
    for (int gi = tid; gi < 1050; gi += 256) {
        const float4* p = (const float4*)(df + gi * 12);
        float4 v0 = p[0], v1 = p[1], v2 = p[2];
        float4 gv = g4[gi];

        a0 = fmaf(gv.x, v0.x, a0); a1 = fmaf(gv.x, v0.y, a1); a2 = fmaf(gv.x, v0.z, a2);
        a0 = fmaf(gv.y, v0.w, a0); a1 = fmaf(gv.y, v1.x, a1); a2 = fmaf(gv.y, v1.y, a2);
        a0 = fmaf(gv.z, v1.z, a0); a1 = fmaf(gv.z, v1.w, a1); a2 = fmaf(gv.z, v2.x, a2);
        a0 = fmaf(gv.w, v2.y, a0); a1 = fmaf(gv.w, v2.z, a1); a2 = fmaf(gv.w, v2.w, a2);
    }

    // wave shuffle reduce (width 64), then cross-wave via LDS
    #pragma unroll
    for (int off = 32; off > 0; off >>= 1) {
        a0 += __shfl_down(a0, off, 64);
        a1 += __shfl_down(a1, off, 64);
        a2 += __shfl_down(a2, off, 64);
    }
    const int wave = tid >> 6, lane = tid & 63;
    if (lane == 0) { red[wave * 3] = a0; red[wave * 3 + 1] = a1; red[wave * 3 + 2] = a2; }
    __syncthreads();
    if (tid < 3) {
        float s = red[tid] + red[3 + tid] + red[6 + tid] + red[9 + tid];
        out[8 + BQ * NATOM + (size_t)ba * 3 + tid] = s;
    }

    // block 0 additionally reduces Etot (8 values) from f32 Ei in ws
    if (blockIdx.x == 0) {
        for (int bb = wave * 2; bb < wave * 2 + 2; ++bb) {
            float s = 0.f;
            for (int i = lane; i < NATOM; i += 64) s += eiF[bb * NATOM + i];
            #pragma unroll
            for (int off = 32; off > 0; off >>= 1) s += __shfl_down(s, off, 64);
            if (lane == 0) out[bb] = s;
        }
    }
}

// ---------------------------------------------------------------- launcher
extern "C" void kernel_launch(void* const* d_in, const int* in_sizes, int n_in,
                              void* d_out, int out_size, void* d_ws, size_t ws_size,
                              hipStream_t stream)
{
    const float* image    = (const float*)d_in[0];
    const float* dfeat    = (const float*)d_in[1];
    const int*   neighbor = (const int*)d_in[2];
    // d_in[3] natoms_img unused
    const float* W0 = (const float*)d_in[4];
    const float* b0 = (const float*)d_in[5];
    const float* W1 = (const float*)d_in[6];
    const float* b1 = (const float*)d_in[7];
    const float* W2 = (const float*)d_in[8];
    const float* b2 = (const float*)d_in[9];

    float* wsf  = (float*)d_ws;
    float* dE   = wsf + WS_DE;
    float* eiF  = wsf + WS_EI;
    float* out  = (float*)d_out;

    hipLaunchKernelGGL(k_ei, dim3(1024), dim3(256), 0, stream,
                       image, W0, b0, W1, b1, W2, b2, dE, eiF, out + 8);
    hipLaunchKernelGGL(k_force, dim3(4096), dim3(256), 0, stream,
                       dfeat, neighbor, dE, eiF, out);
}